// Round 17
// baseline (1060.844 us; speedup 1.0000x reference)
//
#include <hip/hip_runtime.h>
#include <math.h>

#define S_ 1024
#define B_ 8
#define E_ 768
#define D_ 1024
#define H_ 8
#define F_ 2048
#define L_ 4
#define M_ (S_*B_)   // 8192 tokens

typedef unsigned short u16;
typedef unsigned int u32;
typedef u16 u16x8 __attribute__((ext_vector_type(8)));
typedef u16 u16x4 __attribute__((ext_vector_type(4)));
typedef u16 u16x2 __attribute__((ext_vector_type(2)));
typedef u32 u32x2 __attribute__((ext_vector_type(2)));
typedef short bf16x8 __attribute__((ext_vector_type(8)));
typedef float f32x4 __attribute__((ext_vector_type(4)));

#define AS1 __attribute__((address_space(1)))
#define AS3 __attribute__((address_space(3)))

// 1/sqrt(128) * log2(e): folded into Q so softmax uses exp2 directly
#define QSCALE 0.127517432f

__device__ __forceinline__ void gload_lds16(const void* g, void* l) {
  __builtin_amdgcn_global_load_lds((const AS1 void*)g, (AS3 void*)l, 16, 0, 0);
}
__device__ __forceinline__ u16 f2bf(float f) {
  unsigned u = __builtin_bit_cast(unsigned, f);
  return (u16)((u + 0x7fffu + ((u >> 16) & 1u)) >> 16);
}
__device__ __forceinline__ float bf2f(u16 h) {
  unsigned u = ((unsigned)h) << 16;
  return __builtin_bit_cast(float, u);
}
__device__ __forceinline__ u32 cvtpk(float a, float b) {
  u32 r;
  asm("v_cvt_pk_bf16_f32 %0, %1, %2" : "=v"(r) : "v"(a), "v"(b));
  return r;
}

// ---------------- fp32 -> bf16 conversion, 4 tensors per launch -------------
__global__ __launch_bounds__(256) void conv4(
    const float* __restrict__ s0, u16* __restrict__ d0, int n0,
    const float* __restrict__ s1, u16* __restrict__ d1, int n1,
    const float* __restrict__ s2, u16* __restrict__ d2, int n2,
    const float* __restrict__ s3, u16* __restrict__ d3, int n3)
{
  int total = (n0 + n1 + n2 + n3) >> 2;
  for (int i = blockIdx.x * 256 + threadIdx.x; i < total; i += gridDim.x * 256) {
    int e = i << 2;
    const float* s; u16* d; int off;
    if (e < n0)           { s = s0; d = d0; off = e; }
    else if (e < n0+n1)   { s = s1; d = d1; off = e - n0; }
    else if (e < n0+n1+n2){ s = s2; d = d2; off = e - n0 - n1; }
    else                  { s = s3; d = d3; off = e - n0 - n1 - n2; }
    float4 v = *(const float4*)&s[off];
    u16x4 o; o[0]=f2bf(v.x); o[1]=f2bf(v.y); o[2]=f2bf(v.z); o[3]=f2bf(v.w);
    *(u16x4*)&d[off] = o;
  }
}

// -------- gemm32 (qkv only): BM=256, BN=128, BK=32; occupancy-first ----------
// 512 thr (8 waves, 2Mx4N); 3-slot LDS (72KB -> 2 blocks/CU), 2-deep prefetch,
// counted vmcnt(3). Parity swizzle chunk ^= (row>>1)&3 (conflict-free).
template<int ACT, int SCQ>
__global__ __launch_bounds__(512) void gemm32(
    const u16* __restrict__ A, const u16* __restrict__ W,
    const float* __restrict__ bias, u16* __restrict__ Cout,
    int M, int N, int K)
{
  __shared__ u16 lds[36864];             // 3 x (A 8192 | B 4096) u16 = 72KB
  const int gx = gridDim.x, nwg = gx * gridDim.y;
  const int lin = blockIdx.y * gx + blockIdx.x;
  const int work = (lin & 7) * (nwg >> 3) + (lin >> 3);
  const int bm = (work / gx) * 256, bn = (work % gx) * 128;
  const int tid = threadIdx.x;
  const int l = tid & 63;
  const int w = tid >> 6;
  const int l15 = l & 15, lg = l >> 4;
  const int wr = w >> 2, wc = w & 3;     // wave tile 128x32
  const int srow = tid >> 2;             // 0..127 stage row
  const int scb  = tid & 3;              // stage 16B-chunk

  f32x4 acc[8][2] = {};
  const int nt = K >> 5;

#define STAGE_A32(c, k0)                                                    \
  {                                                                         \
    u16* Ab = lds + (c)*12288;                                              \
    _Pragma("unroll")                                                       \
    for (int u = 0; u < 2; ++u) {                                           \
      int row = u*128 + srow;                                               \
      int cb  = scb ^ ((row >> 1) & 3);                                     \
      gload_lds16(A + (size_t)(bm + row) * K + (k0) + cb*8,                 \
                  Ab + u*4096 + tid*8);                                     \
    }                                                                       \
  }
#define STAGE_B32(c, k0)                                                    \
  {                                                                         \
    u16* Bb = lds + (c)*12288 + 8192;                                       \
    int row = srow;                                                         \
    int cb  = scb ^ ((row >> 1) & 3);                                       \
    gload_lds16(W + (size_t)(bn + row) * K + (k0) + cb*8,                   \
                Bb + tid*8);                                                \
  }

  STAGE_A32(0, 0);  STAGE_B32(0, 0);
  STAGE_A32(1, 32); STAGE_B32(1, 32);
  asm volatile("s_waitcnt vmcnt(3)" ::: "memory");
  __builtin_amdgcn_s_barrier();

  int cr = 0, cw = 2;
  for (int t = 0; t < nt; ++t) {
    const u16* Ab = lds + cr*12288;
    const u16* Bb = Ab + 8192;

    bf16x8 bfr[2];
    #pragma unroll
    for (int ni = 0; ni < 2; ++ni) {
      int row = wc*32 + ni*16 + l15;
      bfr[ni] = *(const bf16x8*)&Bb[row*32 + (lg ^ ((row >> 1) & 3))*8];
    }

    {
      bf16x8 af[4];
      #pragma unroll
      for (int mi = 0; mi < 4; ++mi) {
        int row = wr*128 + mi*16 + l15;
        af[mi] = *(const bf16x8*)&Ab[row*32 + (lg ^ ((row >> 1) & 3))*8];
      }
      if (t + 2 < nt) STAGE_A32(cw, (t + 2) << 5);
      #pragma unroll
      for (int mi = 0; mi < 4; ++mi)
        #pragma unroll
        for (int ni = 0; ni < 2; ++ni)
          acc[mi][ni] = __builtin_amdgcn_mfma_f32_16x16x32_bf16(af[mi], bfr[ni], acc[mi][ni], 0, 0, 0);
    }

    {
      bf16x8 af[4];
      #pragma unroll
      for (int mi = 0; mi < 4; ++mi) {
        int row = wr*128 + (4 + mi)*16 + l15;
        af[mi] = *(const bf16x8*)&Ab[row*32 + (lg ^ ((row >> 1) & 3))*8];
      }
      if (t + 2 < nt) STAGE_B32(cw, (t + 2) << 5);
      #pragma unroll
      for (int mi = 0; mi < 4; ++mi)
        #pragma unroll
        for (int ni = 0; ni < 2; ++ni)
          acc[4 + mi][ni] = __builtin_amdgcn_mfma_f32_16x16x32_bf16(af[mi], bfr[ni], acc[4 + mi][ni], 0, 0, 0);
    }

    if (t + 1 < nt) {
      if (t + 2 < nt) { asm volatile("s_waitcnt vmcnt(3)" ::: "memory"); }
      else            { asm volatile("s_waitcnt vmcnt(0)" ::: "memory"); }
      __builtin_amdgcn_s_barrier();
    }
    cr = (cr == 2) ? 0 : cr + 1;
    cw = (cw == 2) ? 0 : cw + 1;
  }
#undef STAGE_A32
#undef STAGE_B32

  #pragma unroll
  for (int ni = 0; ni < 2; ++ni) {
    int col = bn + wc*32 + ni*16 + l15;
    float bv = bias[col];
    #pragma unroll
    for (int mi = 0; mi < 8; ++mi) {
      #pragma unroll
      for (int rr = 0; rr < 4; ++rr) {
        int row = bm + wr*128 + mi*16 + lg*4 + rr;
        float v = acc[mi][ni][rr] + bv;
        if (ACT) v = fmaxf(v, 0.f);
        if (SCQ) { if (col < 1024) v *= QSCALE; }
        Cout[(size_t)row * N + col] = f2bf(v);
      }
    }
  }
}

// -------- gemm256 (r14 measured-best): BM=256,BN=128,BK=64 -------------------
// 3-slot rotating LDS (144KB), 2-deep prefetch, counted vmcnt(6), 2-cluster
// intra-step interleave, T2 swizzle. K/64 >= 3, blocks % 8 == 0.
template<int ACT, int OUTBF, int SCQ, int RES>
__global__ __launch_bounds__(512) void gemm256(
    const u16* __restrict__ A, const u16* __restrict__ W,
    const float* __restrict__ bias, const u16* __restrict__ Rres,
    void* __restrict__ Cout, int M, int N, int K)
{
  __shared__ u16 lds[73728];             // 3 x (A 16384 | B 8192) u16
  const int gx = gridDim.x, nwg = gx * gridDim.y;
  const int lin = blockIdx.y * gx + blockIdx.x;
  const int work = (lin & 7) * (nwg >> 3) + (lin >> 3);
  const int bm = (work / gx) * 256, bn = (work % gx) * 128;
  const int tid = threadIdx.x;
  const int l = tid & 63;
  const int w = tid >> 6;
  const int l15 = l & 15, lg = l >> 4;
  const int wr = w >> 2, wc = w & 3;     // 2 x 4 wave grid
  const int srow = tid >> 3;             // 0..63 stage row within chunk
  const int scb  = tid & 7;              // stage col-block (8 u16 units)

  f32x4 acc[8][2] = {};
  const int nt = K >> 6;

#define STAGE_A(c, k0)                                                      \
  {                                                                         \
    u16* Ab = lds + (c)*24576;                                              \
    _Pragma("unroll")                                                       \
    for (int u = 0; u < 4; ++u) {                                           \
      int row = u*64 + srow;                                                \
      int cb  = scb ^ (row & 7);                                            \
      gload_lds16(A + (size_t)(bm + row) * K + (k0) + cb*8,                 \
                  Ab + u*4096 + tid*8);                                     \
    }                                                                       \
  }
#define STAGE_B(c, k0)                                                      \
  {                                                                         \
    u16* Bb = lds + (c)*24576 + 16384;                                      \
    _Pragma("unroll")                                                       \
    for (int u = 0; u < 2; ++u) {                                           \
      int row = u*64 + srow;                                                \
      int cb  = scb ^ (row & 7);                                            \
      gload_lds16(W + (size_t)(bn + row) * K + (k0) + cb*8,                 \
                  Bb + u*4096 + tid*8);                                     \
    }                                                                       \
  }

  STAGE_A(0, 0);  STAGE_B(0, 0);
  STAGE_A(1, 64); STAGE_B(1, 64);
  asm volatile("s_waitcnt vmcnt(6)" ::: "memory");
  __builtin_amdgcn_s_barrier();

  int cr = 0, cw = 2;
  for (int t = 0; t < nt; ++t) {
    const u16* Ab = lds + cr*24576;
    const u16* Bb = Ab + 16384;

    bf16x8 bfr[2][2];
    #pragma unroll
    for (int ni = 0; ni < 2; ++ni) {
      int row = wc*32 + ni*16 + l15;
      bfr[ni][0] = *(const bf16x8*)&Bb[row*64 + ((lg) ^ (row & 7))*8];
      bfr[ni][1] = *(const bf16x8*)&Bb[row*64 + ((4 + lg) ^ (row & 7))*8];
    }

    {
      bf16x8 af[4][2];
      #pragma unroll
      for (int mi = 0; mi < 4; ++mi) {
        int row = wr*128 + mi*16 + l15;
        af[mi][0] = *(const bf16x8*)&Ab[row*64 + ((lg) ^ (row & 7))*8];
        af[mi][1] = *(const bf16x8*)&Ab[row*64 + ((4 + lg) ^ (row & 7))*8];
      }
      if (t + 2 < nt) STAGE_A(cw, (t + 2) << 6);
      #pragma unroll
      for (int ks = 0; ks < 2; ++ks)
        #pragma unroll
        for (int mi = 0; mi < 4; ++mi)
          #pragma unroll
          for (int ni = 0; ni < 2; ++ni)
            acc[mi][ni] = __builtin_amdgcn_mfma_f32_16x16x32_bf16(af[mi][ks], bfr[ni][ks], acc[mi][ni], 0, 0, 0);
    }

    {
      bf16x8 af[4][2];
      #pragma unroll
      for (int mi = 0; mi < 4; ++mi) {
        int row = wr*128 + (4 + mi)*16 + l15;
        af[mi][0] = *(const bf16x8*)&Ab[row*64 + ((lg) ^ (row & 7))*8];
        af[mi][1] = *(const bf16x8*)&Ab[row*64 + ((4 + lg) ^ (row & 7))*8];
      }
      if (t + 2 < nt) STAGE_B(cw, (t + 2) << 6);
      #pragma unroll
      for (int ks = 0; ks < 2; ++ks)
        #pragma unroll
        for (int mi = 0; mi < 4; ++mi)
          #pragma unroll
          for (int ni = 0; ni < 2; ++ni)
            acc[4 + mi][ni] = __builtin_amdgcn_mfma_f32_16x16x32_bf16(af[mi][ks], bfr[ni][ks], acc[4 + mi][ni], 0, 0, 0);
    }

    if (t + 1 < nt) {
      if (t + 2 < nt) { asm volatile("s_waitcnt vmcnt(6)" ::: "memory"); }
      else            { asm volatile("s_waitcnt vmcnt(0)" ::: "memory"); }
      __builtin_amdgcn_s_barrier();
    }
    cr = (cr == 2) ? 0 : cr + 1;
    cw = (cw == 2) ? 0 : cw + 1;
  }
#undef STAGE_A
#undef STAGE_B

  u16* Cb = (u16*)Cout; float* Cf = (float*)Cout;
  #pragma unroll
  for (int ni = 0; ni < 2; ++ni) {
    int col = bn + wc*32 + ni*16 + l15;
    float bv = bias[col];
    #pragma unroll
    for (int mi = 0; mi < 8; ++mi) {
      #pragma unroll
      for (int rr = 0; rr < 4; ++rr) {
        int row = bm + wr*128 + mi*16 + lg*4 + rr;
        float v = acc[mi][ni][rr] + bv;
        if (RES) v += bf2f(Rres[(size_t)row * N + col]);
        if (ACT) v = fmaxf(v, 0.f);
        if (SCQ) { if (col < 1024) v *= QSCALE; }
        if (OUTBF) Cb[(size_t)row * N + col] = f2bf(v);
        else       Cf[(size_t)row * N + col] = v;
      }
    }
  }
}

// ------------- LayerNorm: Y = LN(X) * g + b, opt ReLU; bf16 io ---------------
template<int NV, bool RELU>
__global__ __launch_bounds__(256) void ln_bf16(
    const u16* __restrict__ X,
    const float* __restrict__ g, const float* __restrict__ b,
    u16* __restrict__ Y)
{
  constexpr int D = NV * 256;
  __shared__ float sbuf[8];
  const int tid = threadIdx.x;
  const size_t base = (size_t)blockIdx.x * D + tid * NV;
  float v[NV];
  if constexpr (NV == 4) {
    u16x4 xv = *(const u16x4*)&X[base];
    #pragma unroll
    for (int i = 0; i < 4; ++i) v[i] = bf2f(xv[i]);
  } else {
    u16x2 xv = *(const u16x2*)&X[base];
    #pragma unroll
    for (int i = 0; i < 2; ++i) v[i] = bf2f(xv[i]);
  }
  float sum = 0.f, sq = 0.f;
  #pragma unroll
  for (int i = 0; i < NV; ++i) { sum += v[i]; sq += v[i]*v[i]; }
  #pragma unroll
  for (int off = 32; off > 0; off >>= 1) {
    sum += __shfl_down(sum, off);
    sq  += __shfl_down(sq, off);
  }
  if ((tid & 63) == 0) { sbuf[tid >> 6] = sum; sbuf[4 + (tid >> 6)] = sq; }
  __syncthreads();
  sum = sbuf[0] + sbuf[1] + sbuf[2] + sbuf[3];
  sq  = sbuf[4] + sbuf[5] + sbuf[6] + sbuf[7];
  const float mean = sum / (float)D;
  const float rstd = rsqrtf(sq / (float)D - mean*mean + 1e-5f);
  const int c0 = tid * NV;
  if constexpr (NV == 4) {
    u16x4 o;
    #pragma unroll
    for (int i = 0; i < 4; ++i) {
      float t = (v[i] - mean) * rstd * g[c0+i] + b[c0+i];
      if (RELU) t = fmaxf(t, 0.f);
      o[i] = f2bf(t);
    }
    *(u16x4*)&Y[base] = o;
  } else {
    u16x2 o;
    #pragma unroll
    for (int i = 0; i < 2; ++i) {
      float t = (v[i] - mean) * rstd * g[c0+i] + b[c0+i];
      if (RELU) t = fmaxf(t, 0.f);
      o[i] = f2bf(t);
    }
    *(u16x2*)&Y[base] = o;
  }
}

// ---------- V transpose: QKV V-part -> Vt[bh][d][s]  (linear, no swizzle) ----
__global__ __launch_bounds__(256) void vtrans(
    const u16* __restrict__ QKV, u16* __restrict__ Vt)
{
  __shared__ u16 Ls[32*132];
  const int st = blockIdx.x, bh = blockIdx.y;
  const int bb = bh >> 3, hh = bh & 7;
  const int t = threadIdx.x;
  #pragma unroll
  for (int i = 0; i < 2; ++i) {
    int e = i*256 + t;
    int s = e >> 4, d0 = (e & 15) * 8;
    u16x8 v = *(const u16x8*)&QKV[(size_t)((st*32 + s)*8 + bb)*3072 + 2048 + hh*128 + d0];
    #pragma unroll
    for (int j = 0; j < 4; ++j) {
      u16x2 p; p[0] = v[2*j]; p[1] = v[2*j+1];
      *(u16x2*)&Ls[s*132 + d0 + 2*j] = p;
    }
  }
  __syncthreads();
  #pragma unroll
  for (int i = 0; i < 2; ++i) {
    int e = i*256 + t;
    int d = e >> 2, s0 = (e & 3) * 8;
    u16x8 v;
    #pragma unroll
    for (int j = 0; j < 8; ++j) v[j] = Ls[(s0+j)*132 + d];
    *(u16x8*)&Vt[(size_t)bh*131072 + (size_t)d*1024 + st*32 + s0] = v;
  }
}

// ---------------- Flash attention, bf16 MFMA (round-9 config) ----------------
__global__ __launch_bounds__(512, 4) void attn_mfma(
    const u16* __restrict__ QKV, const u16* __restrict__ Vt,
    u16* __restrict__ AO)
{
  __shared__ u16 Ks[2][64*128];  // [key][d], d ^= (key&7)<<3
  __shared__ u16 Vs[2][128*64];  // [d][key], key ^= (d&7)<<3
  __shared__ u16 Pl[8][16*64];   // per-wave [q][key], key ^= (q&7)<<3
  const int bid = blockIdx.x;
  const int wg = (bid & 7) * 64 + (bid >> 3);    // bijective: 512 = 8*64
  const int qt = wg & 7, bh = wg >> 3;
  const int bb = bh >> 3, hh = bh & 7;
  const int tid = threadIdx.x, w = tid >> 6, l = tid & 63;
  const int l15 = l & 15, lg = l >> 4;

  bf16x8 aq[4];
  {
    int q = qt*128 + w*16 + l15;
    const u16* qp = QKV + (size_t)(q*8 + bb)*3072 + hh*128 + lg*8;
    #pragma unroll
    for (int kc = 0; kc < 4; ++kc)
      aq[kc] = *(const bf16x8*)(qp + kc*32);
  }
  const u16* vbase = Vt + (size_t)bh*131072;

#define STAGE_KV(c, kt)                                                     \
  {                                                                         \
    _Pragma("unroll")                                                       \
    for (int i = 0; i < 2; ++i) {                                           \
      int e = (w*2 + i) * 512 + l * 8;                                      \
      int krow = e >> 7, d0 = e & 127;                                      \
      int dsw = d0 ^ ((krow & 7) << 3);                                     \
      gload_lds16(QKV + (size_t)(((kt)*64 + krow)*8 + bb)*3072 + 1024       \
                      + hh*128 + dsw,                                       \
                  &Ks[c][(w*2 + i) * 512]);                                 \
      int vd = e >> 6, vc = e & 63;                                         \
      int vsw = vc ^ ((vd & 7) << 3);                                       \
      gload_lds16(vbase + (size_t)vd*1024 + (kt)*64 + vsw,                  \
                  &Vs[c][(w*2 + i) * 512]);                                 \
    }                                                                       \
  }

  f32x4 of[8] = {};
  float mreg = -INFINITY, lpart = 0.f;
  const int psw = (l15 & 7) << 3;

  STAGE_KV(0, 0);
  __syncthreads();

  for (int kt = 0; kt < 16; ++kt) {
    const int cur = kt & 1;
    if (kt + 1 < 16) STAGE_KV(cur ^ 1, kt + 1);

    f32x4 sf[4] = {};
    #pragma unroll
    for (int kc = 0; kc < 4; ++kc) {
      #pragma unroll
      for (int f = 0; f < 4; ++f) {
        int krow = f*16 + l15;
        bf16x8 bk = *(const bf16x8*)&Ks[cur][krow*128 + ((kc*32 + lg*8) ^ ((krow & 7) << 3))];
        sf[f] = __builtin_amdgcn_mfma_f32_16x16x32_bf16(bk, aq[kc], sf[f], 0, 0, 0);
      }
    }

    float pm01 = fmaxf(fmaxf(sf[0][0], sf[0][1]), fmaxf(sf[0][2], sf[0][3]));
    float pm23 = fmaxf(fmaxf(sf[1][0], sf[1][1]), fmaxf(sf[1][2], sf[1][3]));
    float pm45 = fmaxf(fmaxf(sf[2][0], sf[2][1]), fmaxf(sf[2][2], sf[2][3]));
    float pm67 = fmaxf(fmaxf(sf[3][0], sf[3][1]), fmaxf(sf[3][2], sf[3][3]));
    float pmax = fmaxf(fmaxf(pm01, pm23), fmaxf(pm45, pm67));
    pmax = fmaxf(pmax, __shfl_xor(pmax, 16));
    pmax = fmaxf(pmax, __shfl_xor(pmax, 32));

    if (__any(pmax > mreg + 8.f)) {
      float mn = fmaxf(mreg, pmax);
      float al = exp2f(mreg - mn);
      mreg = mn;
      lpart *= al;
      #pragma unroll
      for (int r = 0; r < 4; ++r) {
        float alq = __shfl(al, (l & 48) + lg*4 + r);
        #pragma unroll
        for (int ni = 0; ni < 8; ++ni) of[ni][r] *= alq;
      }
    }

    float psum = 0.f;
    #pragma unroll
    for (int f = 0; f < 4; ++f) {
      float p0 = exp2f(sf[f][0] - mreg);
      float p1 = exp2f(sf[f][1] - mreg);
      float p2 = exp2f(sf[f][2] - mreg);
      float p3 = exp2f(sf[f][3] - mreg);
      psum += (p0 + p1) + (p2 + p3);
      u32x2 pk; pk[0] = cvtpk(p0, p1); pk[1] = cvtpk(p2, p3);
      *(u32x2*)&Pl[w][l15*64 + ((f*16 + lg*4) ^ psw)] = pk;
    }
    lpart += psum;

    bf16x8 pa0 = *(const bf16x8*)&Pl[w][l15*64 + ((lg*8) ^ psw)];
    bf16x8 pa1 = *(const bf16x8*)&Pl[w][l15*64 + ((32 + lg*8) ^ psw)];
    #pragma unroll
    for (int ni = 0; ni < 8; ++ni) {
      int n = ni*16 + l15;
      int nsw = (n & 7) << 3;
      bf16x8 vb0 = *(const bf16x8*)&Vs[cur][n*64 + ((lg*8) ^ nsw)];
      bf16x8 vb1 = *(const bf16x8*)&Vs[cur][n*64 + ((32 + lg*8) ^ nsw)];
      of[ni] = __builtin_amdgcn_mfma_f32_16x16x32_bf16(pa0, vb0, of[ni], 0, 0, 0);
      of[ni] = __builtin_amdgcn_mfma_f32_16x16x32_bf16(pa1, vb1, of[ni], 0, 0, 0);
    }

    if (kt + 1 < 16) __syncthreads();
  }
#undef STAGE_KV

  float ls = lpart;
  ls += __shfl_xor(ls, 16);
  ls += __shfl_xor(ls, 32);
  float inv = 1.f / ls;
  #pragma unroll
  for (int r = 0; r < 4; ++r) {
    float invq = __shfl(inv, (l & 48) + lg*4 + r);
    int q = qt*128 + w*16 + lg*4 + r;
    size_t base = (size_t)(q*8 + bb) * 1024 + hh*128;
    #pragma unroll
    for (int ni = 0; ni < 8; ++ni)
      AO[base + ni*16 + l15] = f2bf(of[ni][r] * invq);
  }
}

// ------------------------- workspace layout (u16 units) ----------------------
#define O_WENC  0ull
#define O_WDEC1 786432ull
#define O_WDEC2 1310720ull
#define O_WLQ   1703936ull
#define O_WLO   4849664ull
#define O_WLF1  5898240ull
#define O_WLF2  7995392ull
#define O_R     10092544ull
#define O_H     35258368ull
#define O_AO    43646976ull
#define O_VT    52035584ull

extern "C" void kernel_launch(void* const* d_in, const int* in_sizes, int n_in,
                              void* d_out, int out_size, void* d_ws, size_t ws_size,
                              hipStream_t stream) {
  (void)in_sizes; (void)n_in; (void)out_size; (void)ws_size;
  const float* x        = (const float*)d_in[0];
  const float* enc_w    = (const float*)d_in[1];
  const float* enc_b    = (const float*)d_in[2];
  const float* enc_ln_g = (const float*)d_in[3];
  const float* enc_ln_b = (const float*)d_in[4];
  const float* qkv_w    = (const float*)d_in[5];
  const float* qkv_b    = (const float*)d_in[6];
  const float* out_w    = (const float*)d_in[7];
  const float* out_b    = (const float*)d_in[8];
  const float* ln1_g    = (const float*)d_in[9];
  const float* ln1_b    = (const float*)d_in[10];
  const float* ff1_w    = (const float*)d_in[11];
  const float* ff1_b    = (const float*)d_in[12];
  const float* ff2_w    = (const float*)d_in[13];
  const float* ff2_b    = (const float*)d_in[14];
  const float* ln2_g    = (const float*)d_in[15];
  const float* ln2_b    = (const float*)d_in[16];
  const float* dec_w1   = (const float*)d_in[17];
  const float* dec_b1   = (const float*)d_in[18];
  const float* dec_ln_g = (const float*)d_in[19];
  const float* dec_ln_b = (const float*)d_in[20];
  const float* dec_w2   = (const float*)d_in[21];
  const float* dec_b2   = (const float*)d_in[22];

  u16* ws16 = (u16*)d_ws;
  u16* wenc  = ws16 + O_WENC;
  u16* wdec1 = ws16 + O_WDEC1;
  u16* wdec2 = ws16 + O_WDEC2;
  u16* wlq   = ws16 + O_WLQ;
  u16* wlo   = ws16 + O_WLO;
  u16* wlf1  = ws16 + O_WLF1;
  u16* wlf2  = ws16 + O_WLF2;
  u16* qkv   = ws16 + O_R;                 // 8192 x 3072
  u16* bufY  = ws16 + O_R;                 // 8192 x 1024
  u16* bufG  = ws16 + O_R + 8388608ull;    // 8192 x 2048 / xb / dech
  u16* xb    = bufG;
  u16* dech  = bufG;
  u16* h     = ws16 + O_H;
  u16* ao    = ws16 + O_AO;
  u16* vt    = ws16 + O_VT;

  const dim3 blk(256);
  const dim3 blk5(512);

  // weights/input -> bf16 (encoder + decoder)
  conv4<<<1024, blk, 0, stream>>>(x, xb, 8192*768,
                                  enc_w, wenc, 1024*768,
                                  dec_w1, wdec1, 512*1024,
                                  dec_w2, wdec2, 768*512);
  // encoder MLP
  gemm256<0,1,0,0><<<dim3(8,32), blk5, 0, stream>>>(xb, wenc, enc_b, nullptr, bufY, M_, 1024, 768);
  ln_bf16<4,true><<<M_, blk, 0, stream>>>(bufY, enc_ln_g, enc_ln_b, h);

  for (int l = 0; l < L_; ++l) {
    conv4<<<1024, blk, 0, stream>>>(qkv_w + (size_t)l*3145728, wlq, 3145728,
                                    out_w + (size_t)l*1048576, wlo, 1048576,
                                    ff1_w + (size_t)l*2097152, wlf1, 2097152,
                                    ff2_w + (size_t)l*2097152, wlf2, 2097152);
    gemm32<0,1><<<dim3(24,32), blk5, 0, stream>>>(h, wlq, qkv_b + (size_t)l*3072, qkv, M_, 3072, 1024);
    vtrans<<<dim3(32,64), blk, 0, stream>>>(qkv, vt);
    attn_mfma<<<512, blk5, 0, stream>>>(qkv, vt, ao);
    gemm256<0,1,0,1><<<dim3(8,32), blk5, 0, stream>>>(ao, wlo, out_b + (size_t)l*1024, h, bufY, M_, 1024, 1024);
    ln_bf16<4,false><<<M_, blk, 0, stream>>>(bufY, ln1_g + (size_t)l*1024, ln1_b + (size_t)l*1024, h);
    gemm256<1,1,0,0><<<dim3(16,32), blk5, 0, stream>>>(h, wlf1, ff1_b + (size_t)l*2048, nullptr, bufG, M_, 2048, 1024);
    gemm256<0,1,0,1><<<dim3(8,32), blk5, 0, stream>>>(bufG, wlf2, ff2_b + (size_t)l*1024, h, bufY, M_, 1024, 2048);
    ln_bf16<4,false><<<M_, blk, 0, stream>>>(bufY, ln2_g + (size_t)l*1024, ln2_b + (size_t)l*1024, h);
  }

  // decoder MLP
  gemm256<0,1,0,0><<<dim3(4,32), blk5, 0, stream>>>(h, wdec1, dec_b1, nullptr, bufY, M_, 512, 1024);
  ln_bf16<2,true><<<M_, blk, 0, stream>>>(bufY, dec_ln_g, dec_ln_b, dech);
  gemm256<0,0,0,0><<<dim3(6,32), blk5, 0, stream>>>(dech, wdec2, dec_b2, nullptr, d_out, M_, 768, 512);
}

// Round 18
// 1028.084 us; speedup vs baseline: 1.0319x; 1.0319x over previous
//
#include <hip/hip_runtime.h>
#include <math.h>

#define S_ 1024
#define B_ 8
#define E_ 768
#define D_ 1024
#define H_ 8
#define F_ 2048
#define L_ 4
#define M_ (S_*B_)   // 8192 tokens

typedef unsigned short u16;
typedef unsigned int u32;
typedef u16 u16x8 __attribute__((ext_vector_type(8)));
typedef u16 u16x4 __attribute__((ext_vector_type(4)));
typedef u16 u16x2 __attribute__((ext_vector_type(2)));
typedef u32 u32x2 __attribute__((ext_vector_type(2)));
typedef short bf16x8 __attribute__((ext_vector_type(8)));
typedef float f32x4 __attribute__((ext_vector_type(4)));

#define AS1 __attribute__((address_space(1)))
#define AS3 __attribute__((address_space(3)))

// 1/sqrt(128) * log2(e): folded into Q so softmax uses exp2 directly
#define QSCALE 0.127517432f

__device__ __forceinline__ void gload_lds16(const void* g, void* l) {
  __builtin_amdgcn_global_load_lds((const AS1 void*)g, (AS3 void*)l, 16, 0, 0);
}
__device__ __forceinline__ u16 f2bf(float f) {
  unsigned u = __builtin_bit_cast(unsigned, f);
  return (u16)((u + 0x7fffu + ((u >> 16) & 1u)) >> 16);
}
__device__ __forceinline__ float bf2f(u16 h) {
  unsigned u = ((unsigned)h) << 16;
  return __builtin_bit_cast(float, u);
}
__device__ __forceinline__ u32 cvtpk(float a, float b) {
  u32 r;
  asm("v_cvt_pk_bf16_f32 %0, %1, %2" : "=v"(r) : "v"(a), "v"(b));
  return r;
}

// ---------------- fp32 -> bf16 conversion, 4 tensors per launch -------------
__global__ __launch_bounds__(256) void conv4(
    const float* __restrict__ s0, u16* __restrict__ d0, int n0,
    const float* __restrict__ s1, u16* __restrict__ d1, int n1,
    const float* __restrict__ s2, u16* __restrict__ d2, int n2,
    const float* __restrict__ s3, u16* __restrict__ d3, int n3)
{
  int total = (n0 + n1 + n2 + n3) >> 2;
  for (int i = blockIdx.x * 256 + threadIdx.x; i < total; i += gridDim.x * 256) {
    int e = i << 2;
    const float* s; u16* d; int off;
    if (e < n0)           { s = s0; d = d0; off = e; }
    else if (e < n0+n1)   { s = s1; d = d1; off = e - n0; }
    else if (e < n0+n1+n2){ s = s2; d = d2; off = e - n0 - n1; }
    else                  { s = s3; d = d3; off = e - n0 - n1 - n2; }
    float4 v = *(const float4*)&s[off];
    u16x4 o; o[0]=f2bf(v.x); o[1]=f2bf(v.y); o[2]=f2bf(v.z); o[3]=f2bf(v.w);
    *(u16x4*)&d[off] = o;
  }
}

// -------- big-tile MFMA GEMM: C[M,N] = A[M,K] @ W[N,K]^T + bias (+R) ---------
// BM=256, BN=128, BK=64; 512 thr (8 waves, 2Mx4N); 3-slot rotating LDS
// (144KB), 2-tile-deep prefetch, counted s_waitcnt vmcnt(6) (never 0 in the
// main loop). Inner K-step split into 2 mi-half clusters with JIT ds_reads and
// stage-issue interleaved (no extra barriers -- sync skeleton unchanged).
// T2 XOR swizzle both-sides. K/64 >= 3, grid blocks % 8 == 0.
template<int ACT, int OUTBF, int SCQ, int RES>
__global__ __launch_bounds__(512) void gemm256(
    const u16* __restrict__ A, const u16* __restrict__ W,
    const float* __restrict__ bias, const u16* __restrict__ Rres,
    void* __restrict__ Cout, int M, int N, int K)
{
  __shared__ u16 lds[73728];             // 3 x (A 16384 | B 8192) u16
  const int gx = gridDim.x, nwg = gx * gridDim.y;
  const int lin = blockIdx.y * gx + blockIdx.x;
  const int work = (lin & 7) * (nwg >> 3) + (lin >> 3);
  const int bm = (work / gx) * 256, bn = (work % gx) * 128;
  const int tid = threadIdx.x;
  const int l = tid & 63;
  const int w = tid >> 6;
  const int l15 = l & 15, lg = l >> 4;
  const int wr = w >> 2, wc = w & 3;     // 2 x 4 wave grid
  const int srow = tid >> 3;             // 0..63 stage row within chunk
  const int scb  = tid & 7;              // stage col-block (8 u16 units)

  f32x4 acc[8][2] = {};
  const int nt = K >> 6;

#define STAGE_A(c, k0)                                                      \
  {                                                                         \
    u16* Ab = lds + (c)*24576;                                              \
    _Pragma("unroll")                                                       \
    for (int u = 0; u < 4; ++u) {                                           \
      int row = u*64 + srow;                                                \
      int cb  = scb ^ (row & 7);                                            \
      gload_lds16(A + (size_t)(bm + row) * K + (k0) + cb*8,                 \
                  Ab + u*4096 + tid*8);                                     \
    }                                                                       \
  }
#define STAGE_B(c, k0)                                                      \
  {                                                                         \
    u16* Bb = lds + (c)*24576 + 16384;                                      \
    _Pragma("unroll")                                                       \
    for (int u = 0; u < 2; ++u) {                                           \
      int row = u*64 + srow;                                                \
      int cb  = scb ^ (row & 7);                                            \
      gload_lds16(W + (size_t)(bn + row) * K + (k0) + cb*8,                 \
                  Bb + u*4096 + tid*8);                                     \
    }                                                                       \
  }

  STAGE_A(0, 0);  STAGE_B(0, 0);
  STAGE_A(1, 64); STAGE_B(1, 64);
  asm volatile("s_waitcnt vmcnt(6)" ::: "memory");
  __builtin_amdgcn_s_barrier();

  int cr = 0, cw = 2;
  for (int t = 0; t < nt; ++t) {
    const u16* Ab = lds + cr*24576;
    const u16* Bb = Ab + 16384;

    // B fragments (shared by both clusters)
    bf16x8 bfr[2][2];
    #pragma unroll
    for (int ni = 0; ni < 2; ++ni) {
      int row = wc*32 + ni*16 + l15;
      bfr[ni][0] = *(const bf16x8*)&Bb[row*64 + ((lg) ^ (row & 7))*8];
      bfr[ni][1] = *(const bf16x8*)&Bb[row*64 + ((4 + lg) ^ (row & 7))*8];
    }

    // cluster 0: mi 0..3  (JIT A-reads, then issue next-tile A stage)
    {
      bf16x8 af[4][2];
      #pragma unroll
      for (int mi = 0; mi < 4; ++mi) {
        int row = wr*128 + mi*16 + l15;
        af[mi][0] = *(const bf16x8*)&Ab[row*64 + ((lg) ^ (row & 7))*8];
        af[mi][1] = *(const bf16x8*)&Ab[row*64 + ((4 + lg) ^ (row & 7))*8];
      }
      if (t + 2 < nt) STAGE_A(cw, (t + 2) << 6);
      #pragma unroll
      for (int ks = 0; ks < 2; ++ks)
        #pragma unroll
        for (int mi = 0; mi < 4; ++mi)
          #pragma unroll
          for (int ni = 0; ni < 2; ++ni)
            acc[mi][ni] = __builtin_amdgcn_mfma_f32_16x16x32_bf16(af[mi][ks], bfr[ni][ks], acc[mi][ni], 0, 0, 0);
    }

    // cluster 1: mi 4..7  (JIT A-reads, then issue next-tile B stage)
    {
      bf16x8 af[4][2];
      #pragma unroll
      for (int mi = 0; mi < 4; ++mi) {
        int row = wr*128 + (4 + mi)*16 + l15;
        af[mi][0] = *(const bf16x8*)&Ab[row*64 + ((lg) ^ (row & 7))*8];
        af[mi][1] = *(const bf16x8*)&Ab[row*64 + ((4 + lg) ^ (row & 7))*8];
      }
      if (t + 2 < nt) STAGE_B(cw, (t + 2) << 6);
      #pragma unroll
      for (int ks = 0; ks < 2; ++ks)
        #pragma unroll
        for (int mi = 0; mi < 4; ++mi)
          #pragma unroll
          for (int ni = 0; ni < 2; ++ni)
            acc[4 + mi][ni] = __builtin_amdgcn_mfma_f32_16x16x32_bf16(af[mi][ks], bfr[ni][ks], acc[4 + mi][ni], 0, 0, 0);
    }

    if (t + 1 < nt) {
      if (t + 2 < nt) { asm volatile("s_waitcnt vmcnt(6)" ::: "memory"); }
      else            { asm volatile("s_waitcnt vmcnt(0)" ::: "memory"); }
      __builtin_amdgcn_s_barrier();
    }
    cr = (cr == 2) ? 0 : cr + 1;
    cw = (cw == 2) ? 0 : cw + 1;
  }
#undef STAGE_A
#undef STAGE_B

  u16* Cb = (u16*)Cout; float* Cf = (float*)Cout;
  #pragma unroll
  for (int ni = 0; ni < 2; ++ni) {
    int col = bn + wc*32 + ni*16 + l15;
    float bv = bias[col];
    #pragma unroll
    for (int mi = 0; mi < 8; ++mi) {
      #pragma unroll
      for (int rr = 0; rr < 4; ++rr) {
        int row = bm + wr*128 + mi*16 + lg*4 + rr;
        float v = acc[mi][ni][rr] + bv;
        if (RES) v += bf2f(Rres[(size_t)row * N + col]);
        if (ACT) v = fmaxf(v, 0.f);
        if (SCQ) { if (col < 1024) v *= QSCALE; }
        if (OUTBF) Cb[(size_t)row * N + col] = f2bf(v);
        else       Cf[(size_t)row * N + col] = v;
      }
    }
  }
}

// ------------- LayerNorm: Y = LN(X) * g + b, opt ReLU; bf16 io ---------------
template<int NV, bool RELU>
__global__ __launch_bounds__(256) void ln_bf16(
    const u16* __restrict__ X,
    const float* __restrict__ g, const float* __restrict__ b,
    u16* __restrict__ Y)
{
  constexpr int D = NV * 256;
  __shared__ float sbuf[8];
  const int tid = threadIdx.x;
  const size_t base = (size_t)blockIdx.x * D + tid * NV;
  float v[NV];
  if constexpr (NV == 4) {
    u16x4 xv = *(const u16x4*)&X[base];
    #pragma unroll
    for (int i = 0; i < 4; ++i) v[i] = bf2f(xv[i]);
  } else {
    u16x2 xv = *(const u16x2*)&X[base];
    #pragma unroll
    for (int i = 0; i < 2; ++i) v[i] = bf2f(xv[i]);
  }
  float sum = 0.f, sq = 0.f;
  #pragma unroll
  for (int i = 0; i < NV; ++i) { sum += v[i]; sq += v[i]*v[i]; }
  #pragma unroll
  for (int off = 32; off > 0; off >>= 1) {
    sum += __shfl_down(sum, off);
    sq  += __shfl_down(sq, off);
  }
  if ((tid & 63) == 0) { sbuf[tid >> 6] = sum; sbuf[4 + (tid >> 6)] = sq; }
  __syncthreads();
  sum = sbuf[0] + sbuf[1] + sbuf[2] + sbuf[3];
  sq  = sbuf[4] + sbuf[5] + sbuf[6] + sbuf[7];
  const float mean = sum / (float)D;
  const float rstd = rsqrtf(sq / (float)D - mean*mean + 1e-5f);
  const int c0 = tid * NV;
  if constexpr (NV == 4) {
    u16x4 o;
    #pragma unroll
    for (int i = 0; i < 4; ++i) {
      float t = (v[i] - mean) * rstd * g[c0+i] + b[c0+i];
      if (RELU) t = fmaxf(t, 0.f);
      o[i] = f2bf(t);
    }
    *(u16x4*)&Y[base] = o;
  } else {
    u16x2 o;
    #pragma unroll
    for (int i = 0; i < 2; ++i) {
      float t = (v[i] - mean) * rstd * g[c0+i] + b[c0+i];
      if (RELU) t = fmaxf(t, 0.f);
      o[i] = f2bf(t);
    }
    *(u16x2*)&Y[base] = o;
  }
}

// ---------- V transpose: QKV V-part -> Vt[bh][d][s]  (linear, no swizzle) ----
__global__ __launch_bounds__(256) void vtrans(
    const u16* __restrict__ QKV, u16* __restrict__ Vt)
{
  __shared__ u16 Ls[32*132];
  const int st = blockIdx.x, bh = blockIdx.y;
  const int bb = bh >> 3, hh = bh & 7;
  const int t = threadIdx.x;
  #pragma unroll
  for (int i = 0; i < 2; ++i) {
    int e = i*256 + t;
    int s = e >> 4, d0 = (e & 15) * 8;
    u16x8 v = *(const u16x8*)&QKV[(size_t)((st*32 + s)*8 + bb)*3072 + 2048 + hh*128 + d0];
    #pragma unroll
    for (int j = 0; j < 4; ++j) {
      u16x2 p; p[0] = v[2*j]; p[1] = v[2*j+1];
      *(u16x2*)&Ls[s*132 + d0 + 2*j] = p;
    }
  }
  __syncthreads();
  #pragma unroll
  for (int i = 0; i < 2; ++i) {
    int e = i*256 + t;
    int d = e >> 2, s0 = (e & 3) * 8;
    u16x8 v;
    #pragma unroll
    for (int j = 0; j < 8; ++j) v[j] = Ls[(s0+j)*132 + d];
    *(u16x8*)&Vt[(size_t)bh*131072 + (size_t)d*1024 + st*32 + s0] = v;
  }
}

// ---------------- Flash attention, bf16 MFMA (round-9 config) ----------------
// grid 512 (XCD-swizzled -> qt 0..7, bh 0..63). block 512 = 8 waves x 16 q.
// QBLK=128, KVBLK=64. Double-buffered K/V (prefetch-before-compute, one
// __syncthreads per tile). Swapped QK^T + in-lane softmax + defer-max.
__global__ __launch_bounds__(512, 4) void attn_mfma(
    const u16* __restrict__ QKV, const u16* __restrict__ Vt,
    u16* __restrict__ AO)
{
  __shared__ u16 Ks[2][64*128];  // [key][d], d ^= (key&7)<<3
  __shared__ u16 Vs[2][128*64];  // [d][key], key ^= (d&7)<<3
  __shared__ u16 Pl[8][16*64];   // per-wave [q][key], key ^= (q&7)<<3
  const int bid = blockIdx.x;
  const int wg = (bid & 7) * 64 + (bid >> 3);    // bijective: 512 = 8*64
  const int qt = wg & 7, bh = wg >> 3;
  const int bb = bh >> 3, hh = bh & 7;
  const int tid = threadIdx.x, w = tid >> 6, l = tid & 63;
  const int l15 = l & 15, lg = l >> 4;

  bf16x8 aq[4];
  {
    int q = qt*128 + w*16 + l15;
    const u16* qp = QKV + (size_t)(q*8 + bb)*3072 + hh*128 + lg*8;
    #pragma unroll
    for (int kc = 0; kc < 4; ++kc)
      aq[kc] = *(const bf16x8*)(qp + kc*32);
  }
  const u16* vbase = Vt + (size_t)bh*131072;

#define STAGE_KV(c, kt)                                                     \
  {                                                                         \
    _Pragma("unroll")                                                       \
    for (int i = 0; i < 2; ++i) {                                           \
      int e = (w*2 + i) * 512 + l * 8;                                      \
      int krow = e >> 7, d0 = e & 127;                                      \
      int dsw = d0 ^ ((krow & 7) << 3);                                     \
      gload_lds16(QKV + (size_t)(((kt)*64 + krow)*8 + bb)*3072 + 1024       \
                      + hh*128 + dsw,                                       \
                  &Ks[c][(w*2 + i) * 512]);                                 \
      int vd = e >> 6, vc = e & 63;                                         \
      int vsw = vc ^ ((vd & 7) << 3);                                       \
      gload_lds16(vbase + (size_t)vd*1024 + (kt)*64 + vsw,                  \
                  &Vs[c][(w*2 + i) * 512]);                                 \
    }                                                                       \
  }

  f32x4 of[8] = {};
  float mreg = -INFINITY, lpart = 0.f;
  const int psw = (l15 & 7) << 3;

  STAGE_KV(0, 0);
  __syncthreads();

  for (int kt = 0; kt < 16; ++kt) {
    const int cur = kt & 1;
    if (kt + 1 < 16) STAGE_KV(cur ^ 1, kt + 1);

    // S^T = mfma(K, Q): lane(l15=q, lg) holds S[key=f*16+lg*4+r][q=l15]
    f32x4 sf[4] = {};
    #pragma unroll
    for (int kc = 0; kc < 4; ++kc) {
      #pragma unroll
      for (int f = 0; f < 4; ++f) {
        int krow = f*16 + l15;
        bf16x8 bk = *(const bf16x8*)&Ks[cur][krow*128 + ((kc*32 + lg*8) ^ ((krow & 7) << 3))];
        sf[f] = __builtin_amdgcn_mfma_f32_16x16x32_bf16(bk, aq[kc], sf[f], 0, 0, 0);
      }
    }

    float pm01 = fmaxf(fmaxf(sf[0][0], sf[0][1]), fmaxf(sf[0][2], sf[0][3]));
    float pm23 = fmaxf(fmaxf(sf[1][0], sf[1][1]), fmaxf(sf[1][2], sf[1][3]));
    float pm45 = fmaxf(fmaxf(sf[2][0], sf[2][1]), fmaxf(sf[2][2], sf[2][3]));
    float pm67 = fmaxf(fmaxf(sf[3][0], sf[3][1]), fmaxf(sf[3][2], sf[3][3]));
    float pmax = fmaxf(fmaxf(pm01, pm23), fmaxf(pm45, pm67));
    pmax = fmaxf(pmax, __shfl_xor(pmax, 16));
    pmax = fmaxf(pmax, __shfl_xor(pmax, 32));

    if (__any(pmax > mreg + 8.f)) {
      float mn = fmaxf(mreg, pmax);
      float al = exp2f(mreg - mn);
      mreg = mn;
      lpart *= al;
      #pragma unroll
      for (int r = 0; r < 4; ++r) {
        float alq = __shfl(al, (l & 48) + lg*4 + r);
        #pragma unroll
        for (int ni = 0; ni < 8; ++ni) of[ni][r] *= alq;
      }
    }

    float psum = 0.f;
    #pragma unroll
    for (int f = 0; f < 4; ++f) {
      float p0 = exp2f(sf[f][0] - mreg);
      float p1 = exp2f(sf[f][1] - mreg);
      float p2 = exp2f(sf[f][2] - mreg);
      float p3 = exp2f(sf[f][3] - mreg);
      psum += (p0 + p1) + (p2 + p3);
      u32x2 pk; pk[0] = cvtpk(p0, p1); pk[1] = cvtpk(p2, p3);
      *(u32x2*)&Pl[w][l15*64 + ((f*16 + lg*4) ^ psw)] = pk;
    }
    lpart += psum;

    bf16x8 pa0 = *(const bf16x8*)&Pl[w][l15*64 + ((lg*8) ^ psw)];
    bf16x8 pa1 = *(const bf16x8*)&Pl[w][l15*64 + ((32 + lg*8) ^ psw)];
    #pragma unroll
    for (int ni = 0; ni < 8; ++ni) {
      int n = ni*16 + l15;
      int nsw = (n & 7) << 3;
      bf16x8 vb0 = *(const bf16x8*)&Vs[cur][n*64 + ((lg*8) ^ nsw)];
      bf16x8 vb1 = *(const bf16x8*)&Vs[cur][n*64 + ((32 + lg*8) ^ nsw)];
      of[ni] = __builtin_amdgcn_mfma_f32_16x16x32_bf16(pa0, vb0, of[ni], 0, 0, 0);
      of[ni] = __builtin_amdgcn_mfma_f32_16x16x32_bf16(pa1, vb1, of[ni], 0, 0, 0);
    }

    if (kt + 1 < 16) __syncthreads();
  }
#undef STAGE_KV

  float ls = lpart;
  ls += __shfl_xor(ls, 16);
  ls += __shfl_xor(ls, 32);
  float inv = 1.f / ls;
  #pragma unroll
  for (int r = 0; r < 4; ++r) {
    float invq = __shfl(inv, (l & 48) + lg*4 + r);
    int q = qt*128 + w*16 + lg*4 + r;
    size_t base = (size_t)(q*8 + bb) * 1024 + hh*128;
    #pragma unroll
    for (int ni = 0; ni < 8; ++ni)
      AO[base + ni*16 + l15] = f2bf(of[ni][r] * invq);
  }
}

// ------------------------- workspace layout (u16 units) ----------------------
#define O_WENC  0ull
#define O_WDEC1 786432ull
#define O_WDEC2 1310720ull
#define O_WLQ   1703936ull
#define O_WLO   4849664ull
#define O_WLF1  5898240ull
#define O_WLF2  7995392ull
#define O_R     10092544ull
#define O_H     35258368ull
#define O_AO    43646976ull
#define O_VT    52035584ull

extern "C" void kernel_launch(void* const* d_in, const int* in_sizes, int n_in,
                              void* d_out, int out_size, void* d_ws, size_t ws_size,
                              hipStream_t stream) {
  (void)in_sizes; (void)n_in; (void)out_size; (void)ws_size;
  const float* x        = (const float*)d_in[0];
  const float* enc_w    = (const float*)d_in[1];
  const float* enc_b    = (const float*)d_in[2];
  const float* enc_ln_g = (const float*)d_in[3];
  const float* enc_ln_b = (const float*)d_in[4];
  const float* qkv_w    = (const float*)d_in[5];
  const float* qkv_b    = (const float*)d_in[6];
  const float* out_w    = (const float*)d_in[7];
  const float* out_b    = (const float*)d_in[8];
  const float* ln1_g    = (const float*)d_in[9];
  const float* ln1_b    = (const float*)d_in[10];
  const float* ff1_w    = (const float*)d_in[11];
  const float* ff1_b    = (const float*)d_in[12];
  const float* ff2_w    = (const float*)d_in[13];
  const float* ff2_b    = (const float*)d_in[14];
  const float* ln2_g    = (const float*)d_in[15];
  const float* ln2_b    = (const float*)d_in[16];
  const float* dec_w1   = (const float*)d_in[17];
  const float* dec_b1   = (const float*)d_in[18];
  const float* dec_ln_g = (const float*)d_in[19];
  const float* dec_ln_b = (const float*)d_in[20];
  const float* dec_w2   = (const float*)d_in[21];
  const float* dec_b2   = (const float*)d_in[22];

  u16* ws16 = (u16*)d_ws;
  u16* wenc  = ws16 + O_WENC;
  u16* wdec1 = ws16 + O_WDEC1;
  u16* wdec2 = ws16 + O_WDEC2;
  u16* wlq   = ws16 + O_WLQ;
  u16* wlo   = ws16 + O_WLO;
  u16* wlf1  = ws16 + O_WLF1;
  u16* wlf2  = ws16 + O_WLF2;
  u16* qkv   = ws16 + O_R;                 // 8192 x 3072
  u16* bufY  = ws16 + O_R;                 // 8192 x 1024
  u16* bufG  = ws16 + O_R + 8388608ull;    // 8192 x 2048 / xb / dech
  u16* xb    = bufG;
  u16* dech  = bufG;
  u16* h     = ws16 + O_H;
  u16* ao    = ws16 + O_AO;
  u16* vt    = ws16 + O_VT;

  const dim3 blk(256);
  const dim3 blk5(512);

  // weights/input -> bf16 (encoder + decoder)
  conv4<<<1024, blk, 0, stream>>>(x, xb, 8192*768,
                                  enc_w, wenc, 1024*768,
                                  dec_w1, wdec1, 512*1024,
                                  dec_w2, wdec2, 768*512);
  // encoder MLP
  gemm256<0,1,0,0><<<dim3(8,32), blk5, 0, stream>>>(xb, wenc, enc_b, nullptr, bufY, M_, 1024, 768);
  ln_bf16<4,true><<<M_, blk, 0, stream>>>(bufY, enc_ln_g, enc_ln_b, h);

  for (int l = 0; l < L_; ++l) {
    conv4<<<1024, blk, 0, stream>>>(qkv_w + (size_t)l*3145728, wlq, 3145728,
                                    out_w + (size_t)l*1048576, wlo, 1048576,
                                    ff1_w + (size_t)l*2097152, wlf1, 2097152,
                                    ff2_w + (size_t)l*2097152, wlf2, 2097152);
    gemm256<0,1,1,0><<<dim3(24,32), blk5, 0, stream>>>(h, wlq, qkv_b + (size_t)l*3072, nullptr, qkv, M_, 3072, 1024);
    vtrans<<<dim3(32,64), blk, 0, stream>>>(qkv, vt);
    attn_mfma<<<512, blk5, 0, stream>>>(qkv, vt, ao);
    gemm256<0,1,0,1><<<dim3(8,32), blk5, 0, stream>>>(ao, wlo, out_b + (size_t)l*1024, h, bufY, M_, 1024, 1024);
    ln_bf16<4,false><<<M_, blk, 0, stream>>>(bufY, ln1_g + (size_t)l*1024, ln1_b + (size_t)l*1024, h);
    gemm256<1,1,0,0><<<dim3(16,32), blk5, 0, stream>>>(h, wlf1, ff1_b + (size_t)l*2048, nullptr, bufG, M_, 2048, 1024);
    gemm256<0,1,0,1><<<dim3(8,32), blk5, 0, stream>>>(bufG, wlf2, ff2_b + (size_t)l*1024, h, bufY, M_, 1024, 2048);
    ln_bf16<4,false><<<M_, blk, 0, stream>>>(bufY, ln2_g + (size_t)l*1024, ln2_b + (size_t)l*1024, h);
  }

  // decoder MLP
  gemm256<0,1,0,0><<<dim3(4,32), blk5, 0, stream>>>(h, wdec1, dec_b1, nullptr, bufY, M_, 512, 1024);
  ln_bf16<2,true><<<M_, blk, 0, stream>>>(bufY, dec_ln_g, dec_ln_b, dech);
  gemm256<0,0,0,0><<<dim3(6,32), blk5, 0, stream>>>(dech, wdec2, dec_b2, nullptr, d_out, M_, 768, 512);
}

// Round 19
// 1005.652 us; speedup vs baseline: 1.0549x; 1.0223x over previous
//
#include <hip/hip_runtime.h>
#include <math.h>

#define S_ 1024
#define B_ 8
#define E_ 768
#define D_ 1024
#define H_ 8
#define F_ 2048
#define L_ 4
#define M_ (S_*B_)   // 8192 tokens

typedef unsigned short u16;
typedef unsigned int u32;
typedef u16 u16x8 __attribute__((ext_vector_type(8)));
typedef u16 u16x4 __attribute__((ext_vector_type(4)));
typedef u16 u16x2 __attribute__((ext_vector_type(2)));
typedef u32 u32x2 __attribute__((ext_vector_type(2)));
typedef short bf16x8 __attribute__((ext_vector_type(8)));
typedef float f32x4 __attribute__((ext_vector_type(4)));

#define AS1 __attribute__((address_space(1)))
#define AS3 __attribute__((address_space(3)))

// 1/sqrt(128) * log2(e): folded into Q so softmax uses exp2 directly
#define QSCALE 0.127517432f

__device__ __forceinline__ void gload_lds16(const void* g, void* l) {
  __builtin_amdgcn_global_load_lds((const AS1 void*)g, (AS3 void*)l, 16, 0, 0);
}
__device__ __forceinline__ u16 f2bf(float f) {
  unsigned u = __builtin_bit_cast(unsigned, f);
  return (u16)((u + 0x7fffu + ((u >> 16) & 1u)) >> 16);
}
__device__ __forceinline__ float bf2f(u16 h) {
  unsigned u = ((unsigned)h) << 16;
  return __builtin_bit_cast(float, u);
}
__device__ __forceinline__ u32 cvtpk(float a, float b) {
  u32 r;
  asm("v_cvt_pk_bf16_f32 %0, %1, %2" : "=v"(r) : "v"(a), "v"(b));
  return r;
}

// ---------------- fp32 -> bf16 conversion, 4 tensors per launch -------------
__global__ __launch_bounds__(256) void conv4(
    const float* __restrict__ s0, u16* __restrict__ d0, int n0,
    const float* __restrict__ s1, u16* __restrict__ d1, int n1,
    const float* __restrict__ s2, u16* __restrict__ d2, int n2,
    const float* __restrict__ s3, u16* __restrict__ d3, int n3)
{
  int total = (n0 + n1 + n2 + n3) >> 2;
  for (int i = blockIdx.x * 256 + threadIdx.x; i < total; i += gridDim.x * 256) {
    int e = i << 2;
    const float* s; u16* d; int off;
    if (e < n0)           { s = s0; d = d0; off = e; }
    else if (e < n0+n1)   { s = s1; d = d1; off = e - n0; }
    else if (e < n0+n1+n2){ s = s2; d = d2; off = e - n0 - n1; }
    else                  { s = s3; d = d3; off = e - n0 - n1 - n2; }
    float4 v = *(const float4*)&s[off];
    u16x4 o; o[0]=f2bf(v.x); o[1]=f2bf(v.y); o[2]=f2bf(v.z); o[3]=f2bf(v.w);
    *(u16x4*)&d[off] = o;
  }
}

// -------- big-tile MFMA GEMM: C[M,N] = A[M,K] @ W[N,K]^T + bias (+R) ---------
// BM=256, BN=128, BK=64; 512 thr (8 waves, 2Mx4N); 3-slot rotating LDS
// (144KB), 2-tile-deep prefetch, counted s_waitcnt vmcnt(6) (never 0 in the
// main loop). Intra-step 2-cluster interleave (r14). T2 XOR swizzle.
// VT: blocks with bn >= 2048 write transposed to VtOut[bh][d][s] via LDS
// (the qkv V-part), skipping the row-major C write. K/64>=3, blocks%8==0.
template<int ACT, int OUTBF, int SCQ, int RES, int VT>
__global__ __launch_bounds__(512) void gemm256(
    const u16* __restrict__ A, const u16* __restrict__ W,
    const float* __restrict__ bias, const u16* __restrict__ Rres,
    u16* __restrict__ VtOut, void* __restrict__ Cout, int M, int N, int K)
{
  __shared__ u16 lds[73728];             // 3 x (A 16384 | B 8192) u16
  const int gx = gridDim.x, nwg = gx * gridDim.y;
  const int lin = blockIdx.y * gx + blockIdx.x;
  const int work = (lin & 7) * (nwg >> 3) + (lin >> 3);
  const int bm = (work / gx) * 256, bn = (work % gx) * 128;
  const int tid = threadIdx.x;
  const int l = tid & 63;
  const int w = tid >> 6;
  const int l15 = l & 15, lg = l >> 4;
  const int wr = w >> 2, wc = w & 3;     // 2 x 4 wave grid
  const int srow = tid >> 3;             // 0..63 stage row within chunk
  const int scb  = tid & 7;              // stage col-block (8 u16 units)

  f32x4 acc[8][2] = {};
  const int nt = K >> 6;

#define STAGE_A(c, k0)                                                      \
  {                                                                         \
    u16* Ab = lds + (c)*24576;                                              \
    _Pragma("unroll")                                                       \
    for (int u = 0; u < 4; ++u) {                                           \
      int row = u*64 + srow;                                                \
      int cb  = scb ^ (row & 7);                                            \
      gload_lds16(A + (size_t)(bm + row) * K + (k0) + cb*8,                 \
                  Ab + u*4096 + tid*8);                                     \
    }                                                                       \
  }
#define STAGE_B(c, k0)                                                      \
  {                                                                         \
    u16* Bb = lds + (c)*24576 + 16384;                                      \
    _Pragma("unroll")                                                       \
    for (int u = 0; u < 2; ++u) {                                           \
      int row = u*64 + srow;                                                \
      int cb  = scb ^ (row & 7);                                            \
      gload_lds16(W + (size_t)(bn + row) * K + (k0) + cb*8,                 \
                  Bb + u*4096 + tid*8);                                     \
    }                                                                       \
  }

  STAGE_A(0, 0);  STAGE_B(0, 0);
  STAGE_A(1, 64); STAGE_B(1, 64);
  asm volatile("s_waitcnt vmcnt(6)" ::: "memory");
  __builtin_amdgcn_s_barrier();

  int cr = 0, cw = 2;
  for (int t = 0; t < nt; ++t) {
    const u16* Ab = lds + cr*24576;
    const u16* Bb = Ab + 16384;

    // B fragments (shared by both clusters)
    bf16x8 bfr[2][2];
    #pragma unroll
    for (int ni = 0; ni < 2; ++ni) {
      int row = wc*32 + ni*16 + l15;
      bfr[ni][0] = *(const bf16x8*)&Bb[row*64 + ((lg) ^ (row & 7))*8];
      bfr[ni][1] = *(const bf16x8*)&Bb[row*64 + ((4 + lg) ^ (row & 7))*8];
    }

    // cluster 0: mi 0..3  (JIT A-reads, then issue next-tile A stage)
    {
      bf16x8 af[4][2];
      #pragma unroll
      for (int mi = 0; mi < 4; ++mi) {
        int row = wr*128 + mi*16 + l15;
        af[mi][0] = *(const bf16x8*)&Ab[row*64 + ((lg) ^ (row & 7))*8];
        af[mi][1] = *(const bf16x8*)&Ab[row*64 + ((4 + lg) ^ (row & 7))*8];
      }
      if (t + 2 < nt) STAGE_A(cw, (t + 2) << 6);
      #pragma unroll
      for (int ks = 0; ks < 2; ++ks)
        #pragma unroll
        for (int mi = 0; mi < 4; ++mi)
          #pragma unroll
          for (int ni = 0; ni < 2; ++ni)
            acc[mi][ni] = __builtin_amdgcn_mfma_f32_16x16x32_bf16(af[mi][ks], bfr[ni][ks], acc[mi][ni], 0, 0, 0);
    }

    // cluster 1: mi 4..7  (JIT A-reads, then issue next-tile B stage)
    {
      bf16x8 af[4][2];
      #pragma unroll
      for (int mi = 0; mi < 4; ++mi) {
        int row = wr*128 + (4 + mi)*16 + l15;
        af[mi][0] = *(const bf16x8*)&Ab[row*64 + ((lg) ^ (row & 7))*8];
        af[mi][1] = *(const bf16x8*)&Ab[row*64 + ((4 + lg) ^ (row & 7))*8];
      }
      if (t + 2 < nt) STAGE_B(cw, (t + 2) << 6);
      #pragma unroll
      for (int ks = 0; ks < 2; ++ks)
        #pragma unroll
        for (int mi = 0; mi < 4; ++mi)
          #pragma unroll
          for (int ni = 0; ni < 2; ++ni)
            acc[4 + mi][ni] = __builtin_amdgcn_mfma_f32_16x16x32_bf16(af[mi][ks], bfr[ni][ks], acc[4 + mi][ni], 0, 0, 0);
    }

    if (t + 1 < nt) {
      if (t + 2 < nt) { asm volatile("s_waitcnt vmcnt(6)" ::: "memory"); }
      else            { asm volatile("s_waitcnt vmcnt(0)" ::: "memory"); }
      __builtin_amdgcn_s_barrier();
    }
    cr = (cr == 2) ? 0 : cr + 1;
    cw = (cw == 2) ? 0 : cw + 1;
  }
#undef STAGE_A
#undef STAGE_B

  if (VT && bn >= 2048) {
    // V-part of qkv: write Vt[bh = b*8+hh][d][s] via LDS transpose.
    // ldt layout: [(bb*128 + d)*40 + s_local], pad 40 (16B-aligned rows,
    // d-stride 80B spreads banks). All staging loads drained; barrier
    // covers cross-wave ds_read completion before LDS reuse.
    const int hh = (bn - 2048) >> 7;
    u16* ldt = lds;                       // 1024*40 = 40960 u16 <= 73728
    __syncthreads();
    #pragma unroll
    for (int ni = 0; ni < 2; ++ni) {
      int d = wc*32 + ni*16 + l15;
      float bv = bias[bn + d];
      #pragma unroll
      for (int mi = 0; mi < 8; ++mi) {
        #pragma unroll
        for (int rr = 0; rr < 4; ++rr) {
          int lt = wr*128 + mi*16 + lg*4 + rr;    // local token 0..255
          ldt[((lt & 7)*128 + d)*40 + (lt >> 3)] = f2bf(acc[mi][ni][rr] + bv);
        }
      }
    }
    __syncthreads();
    const int sbase = bm >> 3;                    // 32 s-rows per tile
    #pragma unroll
    for (int pass = 0; pass < 8; ++pass) {
      int bbd = pass*128 + (tid >> 2);            // bb*128 + d, 0..1023
      int sg  = tid & 3;
      int bb  = bbd >> 7, d = bbd & 127;
      u16x8 vv = *(const u16x8*)&ldt[bbd*40 + sg*8];
      *(u16x8*)&VtOut[(size_t)(bb*8 + hh)*131072 + (size_t)d*1024 + sbase + sg*8] = vv;
    }
    return;
  }

  u16* Cb = (u16*)Cout; float* Cf = (float*)Cout;
  #pragma unroll
  for (int ni = 0; ni < 2; ++ni) {
    int col = bn + wc*32 + ni*16 + l15;
    float bv = bias[col];
    #pragma unroll
    for (int mi = 0; mi < 8; ++mi) {
      #pragma unroll
      for (int rr = 0; rr < 4; ++rr) {
        int row = bm + wr*128 + mi*16 + lg*4 + rr;
        float v = acc[mi][ni][rr] + bv;
        if (RES) v += bf2f(Rres[(size_t)row * N + col]);
        if (ACT) v = fmaxf(v, 0.f);
        if (SCQ) { if (col < 1024) v *= QSCALE; }
        if (OUTBF) Cb[(size_t)row * N + col] = f2bf(v);
        else       Cf[(size_t)row * N + col] = v;
      }
    }
  }
}

// ------------- LayerNorm: Y = LN(X) * g + b, opt ReLU; bf16 io ---------------
template<int NV, bool RELU>
__global__ __launch_bounds__(256) void ln_bf16(
    const u16* __restrict__ X,
    const float* __restrict__ g, const float* __restrict__ b,
    u16* __restrict__ Y)
{
  constexpr int D = NV * 256;
  __shared__ float sbuf[8];
  const int tid = threadIdx.x;
  const size_t base = (size_t)blockIdx.x * D + tid * NV;
  float v[NV];
  if constexpr (NV == 4) {
    u16x4 xv = *(const u16x4*)&X[base];
    #pragma unroll
    for (int i = 0; i < 4; ++i) v[i] = bf2f(xv[i]);
  } else {
    u16x2 xv = *(const u16x2*)&X[base];
    #pragma unroll
    for (int i = 0; i < 2; ++i) v[i] = bf2f(xv[i]);
  }
  float sum = 0.f, sq = 0.f;
  #pragma unroll
  for (int i = 0; i < NV; ++i) { sum += v[i]; sq += v[i]*v[i]; }
  #pragma unroll
  for (int off = 32; off > 0; off >>= 1) {
    sum += __shfl_down(sum, off);
    sq  += __shfl_down(sq, off);
  }
  if ((tid & 63) == 0) { sbuf[tid >> 6] = sum; sbuf[4 + (tid >> 6)] = sq; }
  __syncthreads();
  sum = sbuf[0] + sbuf[1] + sbuf[2] + sbuf[3];
  sq  = sbuf[4] + sbuf[5] + sbuf[6] + sbuf[7];
  const float mean = sum / (float)D;
  const float rstd = rsqrtf(sq / (float)D - mean*mean + 1e-5f);
  const int c0 = tid * NV;
  if constexpr (NV == 4) {
    u16x4 o;
    #pragma unroll
    for (int i = 0; i < 4; ++i) {
      float t = (v[i] - mean) * rstd * g[c0+i] + b[c0+i];
      if (RELU) t = fmaxf(t, 0.f);
      o[i] = f2bf(t);
    }
    *(u16x4*)&Y[base] = o;
  } else {
    u16x2 o;
    #pragma unroll
    for (int i = 0; i < 2; ++i) {
      float t = (v[i] - mean) * rstd * g[c0+i] + b[c0+i];
      if (RELU) t = fmaxf(t, 0.f);
      o[i] = f2bf(t);
    }
    *(u16x2*)&Y[base] = o;
  }
}

// ---------------- Flash attention, bf16 MFMA (round-9 config) ----------------
// grid 512 (XCD-swizzled -> qt 0..7, bh 0..63). block 512 = 8 waves x 16 q.
// QBLK=128, KVBLK=64. Double-buffered K/V (prefetch-before-compute, one
// __syncthreads per tile). Swapped QK^T + in-lane softmax + defer-max.
__global__ __launch_bounds__(512, 4) void attn_mfma(
    const u16* __restrict__ QKV, const u16* __restrict__ Vt,
    u16* __restrict__ AO)
{
  __shared__ u16 Ks[2][64*128];  // [key][d], d ^= (key&7)<<3
  __shared__ u16 Vs[2][128*64];  // [d][key], key ^= (d&7)<<3
  __shared__ u16 Pl[8][16*64];   // per-wave [q][key], key ^= (q&7)<<3
  const int bid = blockIdx.x;
  const int wg = (bid & 7) * 64 + (bid >> 3);    // bijective: 512 = 8*64
  const int qt = wg & 7, bh = wg >> 3;
  const int bb = bh >> 3, hh = bh & 7;
  const int tid = threadIdx.x, w = tid >> 6, l = tid & 63;
  const int l15 = l & 15, lg = l >> 4;

  bf16x8 aq[4];
  {
    int q = qt*128 + w*16 + l15;
    const u16* qp = QKV + (size_t)(q*8 + bb)*3072 + hh*128 + lg*8;
    #pragma unroll
    for (int kc = 0; kc < 4; ++kc)
      aq[kc] = *(const bf16x8*)(qp + kc*32);
  }
  const u16* vbase = Vt + (size_t)bh*131072;

#define STAGE_KV(c, kt)                                                     \
  {                                                                         \
    _Pragma("unroll")                                                       \
    for (int i = 0; i < 2; ++i) {                                           \
      int e = (w*2 + i) * 512 + l * 8;                                      \
      int krow = e >> 7, d0 = e & 127;                                      \
      int dsw = d0 ^ ((krow & 7) << 3);                                     \
      gload_lds16(QKV + (size_t)(((kt)*64 + krow)*8 + bb)*3072 + 1024       \
                      + hh*128 + dsw,                                       \
                  &Ks[c][(w*2 + i) * 512]);                                 \
      int vd = e >> 6, vc = e & 63;                                         \
      int vsw = vc ^ ((vd & 7) << 3);                                       \
      gload_lds16(vbase + (size_t)vd*1024 + (kt)*64 + vsw,                  \
                  &Vs[c][(w*2 + i) * 512]);                                 \
    }                                                                       \
  }

  f32x4 of[8] = {};
  float mreg = -INFINITY, lpart = 0.f;
  const int psw = (l15 & 7) << 3;

  STAGE_KV(0, 0);
  __syncthreads();

  for (int kt = 0; kt < 16; ++kt) {
    const int cur = kt & 1;
    if (kt + 1 < 16) STAGE_KV(cur ^ 1, kt + 1);

    // S^T = mfma(K, Q): lane(l15=q, lg) holds S[key=f*16+lg*4+r][q=l15]
    f32x4 sf[4] = {};
    #pragma unroll
    for (int kc = 0; kc < 4; ++kc) {
      #pragma unroll
      for (int f = 0; f < 4; ++f) {
        int krow = f*16 + l15;
        bf16x8 bk = *(const bf16x8*)&Ks[cur][krow*128 + ((kc*32 + lg*8) ^ ((krow & 7) << 3))];
        sf[f] = __builtin_amdgcn_mfma_f32_16x16x32_bf16(bk, aq[kc], sf[f], 0, 0, 0);
      }
    }

    float pm01 = fmaxf(fmaxf(sf[0][0], sf[0][1]), fmaxf(sf[0][2], sf[0][3]));
    float pm23 = fmaxf(fmaxf(sf[1][0], sf[1][1]), fmaxf(sf[1][2], sf[1][3]));
    float pm45 = fmaxf(fmaxf(sf[2][0], sf[2][1]), fmaxf(sf[2][2], sf[2][3]));
    float pm67 = fmaxf(fmaxf(sf[3][0], sf[3][1]), fmaxf(sf[3][2], sf[3][3]));
    float pmax = fmaxf(fmaxf(pm01, pm23), fmaxf(pm45, pm67));
    pmax = fmaxf(pmax, __shfl_xor(pmax, 16));
    pmax = fmaxf(pmax, __shfl_xor(pmax, 32));

    if (__any(pmax > mreg + 8.f)) {
      float mn = fmaxf(mreg, pmax);
      float al = exp2f(mreg - mn);
      mreg = mn;
      lpart *= al;
      #pragma unroll
      for (int r = 0; r < 4; ++r) {
        float alq = __shfl(al, (l & 48) + lg*4 + r);
        #pragma unroll
        for (int ni = 0; ni < 8; ++ni) of[ni][r] *= alq;
      }
    }

    float psum = 0.f;
    #pragma unroll
    for (int f = 0; f < 4; ++f) {
      float p0 = exp2f(sf[f][0] - mreg);
      float p1 = exp2f(sf[f][1] - mreg);
      float p2 = exp2f(sf[f][2] - mreg);
      float p3 = exp2f(sf[f][3] - mreg);
      psum += (p0 + p1) + (p2 + p3);
      u32x2 pk; pk[0] = cvtpk(p0, p1); pk[1] = cvtpk(p2, p3);
      *(u32x2*)&Pl[w][l15*64 + ((f*16 + lg*4) ^ psw)] = pk;
    }
    lpart += psum;

    bf16x8 pa0 = *(const bf16x8*)&Pl[w][l15*64 + ((lg*8) ^ psw)];
    bf16x8 pa1 = *(const bf16x8*)&Pl[w][l15*64 + ((32 + lg*8) ^ psw)];
    #pragma unroll
    for (int ni = 0; ni < 8; ++ni) {
      int n = ni*16 + l15;
      int nsw = (n & 7) << 3;
      bf16x8 vb0 = *(const bf16x8*)&Vs[cur][n*64 + ((lg*8) ^ nsw)];
      bf16x8 vb1 = *(const bf16x8*)&Vs[cur][n*64 + ((32 + lg*8) ^ nsw)];
      of[ni] = __builtin_amdgcn_mfma_f32_16x16x32_bf16(pa0, vb0, of[ni], 0, 0, 0);
      of[ni] = __builtin_amdgcn_mfma_f32_16x16x32_bf16(pa1, vb1, of[ni], 0, 0, 0);
    }

    if (kt + 1 < 16) __syncthreads();
  }
#undef STAGE_KV

  float ls = lpart;
  ls += __shfl_xor(ls, 16);
  ls += __shfl_xor(ls, 32);
  float inv = 1.f / ls;
  #pragma unroll
  for (int r = 0; r < 4; ++r) {
    float invq = __shfl(inv, (l & 48) + lg*4 + r);
    int q = qt*128 + w*16 + lg*4 + r;
    size_t base = (size_t)(q*8 + bb) * 1024 + hh*128;
    #pragma unroll
    for (int ni = 0; ni < 8; ++ni)
      AO[base + ni*16 + l15] = f2bf(of[ni][r] * invq);
  }
}

// ------------------------- workspace layout (u16 units) ----------------------
#define O_WENC  0ull
#define O_WDEC1 786432ull
#define O_WDEC2 1310720ull
#define O_WLQ   1703936ull
#define O_WLO   4849664ull
#define O_WLF1  5898240ull
#define O_WLF2  7995392ull
#define O_R     10092544ull
#define O_H     35258368ull
#define O_AO    43646976ull
#define O_VT    52035584ull

extern "C" void kernel_launch(void* const* d_in, const int* in_sizes, int n_in,
                              void* d_out, int out_size, void* d_ws, size_t ws_size,
                              hipStream_t stream) {
  (void)in_sizes; (void)n_in; (void)out_size; (void)ws_size;
  const float* x        = (const float*)d_in[0];
  const float* enc_w    = (const float*)d_in[1];
  const float* enc_b    = (const float*)d_in[2];
  const float* enc_ln_g = (const float*)d_in[3];
  const float* enc_ln_b = (const float*)d_in[4];
  const float* qkv_w    = (const float*)d_in[5];
  const float* qkv_b    = (const float*)d_in[6];
  const float* out_w    = (const float*)d_in[7];
  const float* out_b    = (const float*)d_in[8];
  const float* ln1_g    = (const float*)d_in[9];
  const float* ln1_b    = (const float*)d_in[10];
  const float* ff1_w    = (const float*)d_in[11];
  const float* ff1_b    = (const float*)d_in[12];
  const float* ff2_w    = (const float*)d_in[13];
  const float* ff2_b    = (const float*)d_in[14];
  const float* ln2_g    = (const float*)d_in[15];
  const float* ln2_b    = (const float*)d_in[16];
  const float* dec_w1   = (const float*)d_in[17];
  const float* dec_b1   = (const float*)d_in[18];
  const float* dec_ln_g = (const float*)d_in[19];
  const float* dec_ln_b = (const float*)d_in[20];
  const float* dec_w2   = (const float*)d_in[21];
  const float* dec_b2   = (const float*)d_in[22];

  u16* ws16 = (u16*)d_ws;
  u16* wenc  = ws16 + O_WENC;
  u16* wdec1 = ws16 + O_WDEC1;
  u16* wdec2 = ws16 + O_WDEC2;
  u16* wlq   = ws16 + O_WLQ;
  u16* wlo   = ws16 + O_WLO;
  u16* wlf1  = ws16 + O_WLF1;
  u16* wlf2  = ws16 + O_WLF2;
  u16* qkv   = ws16 + O_R;                 // 8192 x 3072 (V region unused)
  u16* bufY  = ws16 + O_R;                 // 8192 x 1024
  u16* bufG  = ws16 + O_R + 8388608ull;    // 8192 x 2048 / xb / dech
  u16* xb    = bufG;
  u16* dech  = bufG;
  u16* h     = ws16 + O_H;
  u16* ao    = ws16 + O_AO;
  u16* vt    = ws16 + O_VT;

  const dim3 blk(256);
  const dim3 blk5(512);

  // weights/input -> bf16 (encoder + decoder)
  conv4<<<1024, blk, 0, stream>>>(x, xb, 8192*768,
                                  enc_w, wenc, 1024*768,
                                  dec_w1, wdec1, 512*1024,
                                  dec_w2, wdec2, 768*512);
  // encoder MLP
  gemm256<0,1,0,0,0><<<dim3(8,32), blk5, 0, stream>>>(xb, wenc, enc_b, nullptr, nullptr, bufY, M_, 1024, 768);
  ln_bf16<4,true><<<M_, blk, 0, stream>>>(bufY, enc_ln_g, enc_ln_b, h);

  for (int l = 0; l < L_; ++l) {
    conv4<<<1024, blk, 0, stream>>>(qkv_w + (size_t)l*3145728, wlq, 3145728,
                                    out_w + (size_t)l*1048576, wlo, 1048576,
                                    ff1_w + (size_t)l*2097152, wlf1, 2097152,
                                    ff2_w + (size_t)l*2097152, wlf2, 2097152);
    // qkv GEMM: Q/K to qkv buffer; V transposed directly to vt (VT=1)
    gemm256<0,1,1,0,1><<<dim3(24,32), blk5, 0, stream>>>(h, wlq, qkv_b + (size_t)l*3072, nullptr, vt, qkv, M_, 3072, 1024);
    attn_mfma<<<512, blk5, 0, stream>>>(qkv, vt, ao);
    gemm256<0,1,0,1,0><<<dim3(8,32), blk5, 0, stream>>>(ao, wlo, out_b + (size_t)l*1024, h, nullptr, bufY, M_, 1024, 1024);
    ln_bf16<4,false><<<M_, blk, 0, stream>>>(bufY, ln1_g + (size_t)l*1024, ln1_b + (size_t)l*1024, h);
    gemm256<1,1,0,0,0><<<dim3(16,32), blk5, 0, stream>>>(h, wlf1, ff1_b + (size_t)l*2048, nullptr, nullptr, bufG, M_, 2048, 1024);
    gemm256<0,1,0,1,0><<<dim3(8,32), blk5, 0, stream>>>(bufG, wlf2, ff2_b + (size_t)l*1024, h, nullptr, bufY, M_, 1024, 2048);
    ln_bf16<4,false><<<M_, blk, 0, stream>>>(bufY, ln2_g + (size_t)l*1024, ln2_b + (size_t)l*1024, h);
  }

  // decoder MLP
  gemm256<0,1,0,0,0><<<dim3(4,32), blk5, 0, stream>>>(h, wdec1, dec_b1, nullptr, nullptr, bufY, M_, 512, 1024);
  ln_bf16<2,true><<<M_, blk, 0, stream>>>(bufY, dec_ln_g, dec_ln_b, dech);
  gemm256<0,0,0,0,0><<<dim3(6,32), blk5, 0, stream>>>(dech, wdec2, dec_b2, nullptr, nullptr, d_out, M_, 768, 512);
}